// Round 2
// baseline (5474.172 us; speedup 1.0000x reference)
//
#include <hip/hip_runtime.h>
#include <hip/hip_bf16.h>
#include <math.h>

#define NN_ 65536
#define NE_ 131072
#define B_  32
#define T_  4096

__device__ __forceinline__ float gelu_f(float x){
    return 0.5f*x*(1.0f + erff(x*0.70710678118654752f));
}

// monotonic float<->uint encoding for atomicMax on floats
__device__ __forceinline__ unsigned enc_f(float f){
    unsigned b = __float_as_uint(f);
    return (b & 0x80000000u) ? ~b : (b | 0x80000000u);
}
__device__ __forceinline__ float dec_f(unsigned u){
    return (u & 0x80000000u) ? __uint_as_float(u ^ 0x80000000u) : __uint_as_float(~u);
}

// ---------------- zero ----------------
__global__ void k_zero(float* p, int n){
    int i = blockIdx.x*blockDim.x + threadIdx.x;
    int stride = gridDim.x*blockDim.x;
    for(; i<n; i+=stride) p[i] = 0.f;
}

// ---------------- embed concat: h64[n][c] = c<32 ? x[n][c] : emb[nidx[n]][c-32] ----
__global__ void k_embed(const float* __restrict__ x, const int* __restrict__ nidx,
                        const float* __restrict__ emb, float* __restrict__ h64){
    int gid = blockIdx.x*256 + threadIdx.x;
    int n = gid >> 6, c = gid & 63;
    float v = (c < 32) ? x[(size_t)n*32 + c] : emb[(size_t)nidx[n]*32 + (c-32)];
    h64[gid] = v;
}

// ---------------- node GEMM: C[M,128] = A[M,K] @ W[K,128] ----------------
template<int K>
__global__ void k_gemm_node(const float* __restrict__ A, const float* __restrict__ W,
                            float* __restrict__ C){
    int lane = threadIdx.x & 63;
    int wy = threadIdx.x >> 6;
    int r0 = blockIdx.x*16 + wy*4;
    const float* a0 = A + (size_t)r0*K;
    float acc0[4] = {0,0,0,0}, acc1[4] = {0,0,0,0};
    #pragma unroll 4
    for(int k=0;k<K;k+=4){
        float4 av[4];
        #pragma unroll
        for(int i=0;i<4;i++) av[i] = *(const float4*)(a0 + (size_t)i*K + k);
        #pragma unroll
        for(int kk=0;kk<4;kk++){
            float w0 = W[(size_t)(k+kk)*128 + lane];
            float w1 = W[(size_t)(k+kk)*128 + 64 + lane];
            #pragma unroll
            for(int i=0;i<4;i++){
                float a = ((const float*)&av[i])[kk];
                acc0[i] += a*w0;
                acc1[i] += a*w1;
            }
        }
    }
    #pragma unroll
    for(int i=0;i<4;i++){
        C[(size_t)(r0+i)*128 + lane]      = acc0[i];
        C[(size_t)(r0+i)*128 + 64 + lane] = acc1[i];
    }
}

// ---------------- per-row dots: ssrc = hW . a_s, sdst = hW . a_d --------------
__global__ void k_rowdots(const float* __restrict__ hW, const float* __restrict__ as_,
                          const float* __restrict__ ad_, float* __restrict__ ssrc,
                          float* __restrict__ sdst){
    int lane = threadIdx.x & 63;
    int row = blockIdx.x*4 + (threadIdx.x >> 6);
    const float* hp = hW + (size_t)row*128;
    float h0 = hp[lane], h1 = hp[lane+64];
    float d0 = h0*as_[lane] + h1*as_[lane+64];
    float d1 = h0*ad_[lane] + h1*ad_[lane+64];
    #pragma unroll
    for(int off=32; off; off>>=1){
        d0 += __shfl_xor(d0, off);
        d1 += __shfl_xor(d1, off);
    }
    if(lane==0){ ssrc[row] = d0; sdst[row] = d1; }
}

// ---------------- edge pass 1: e = lrelu(ssrc[s]+sdst[d]); max into m[d] ------
__global__ void k_edge1(const int* __restrict__ src, const int* __restrict__ dst,
                        const float* __restrict__ ssrc, const float* __restrict__ sdst,
                        float* __restrict__ ebuf, unsigned* __restrict__ menc){
    int e = blockIdx.x*256 + threadIdx.x;   // e < NE_+NN_
    int s, d;
    if(e < NE_){ s = src[e]; d = dst[e]; } else { s = d = e - NE_; }
    float v = ssrc[s] + sdst[d];
    v = (v > 0.f) ? v : 0.2f*v;
    ebuf[e] = v;
    atomicMax(&menc[d], enc_f(v));
}

// ---------------- edge pass 2: ex = exp(e - m[d]); sum into ssum[d] -----------
__global__ void k_edge2(const int* __restrict__ dst, const unsigned* __restrict__ menc,
                        float* __restrict__ ebuf, float* __restrict__ ssum){
    int e = blockIdx.x*256 + threadIdx.x;
    int d = (e < NE_) ? dst[e] : (e - NE_);
    float m = dec_f(menc[d]);
    float ex = __expf(ebuf[e] - m);
    ebuf[e] = ex;
    atomicAdd(&ssum[d], ex);
}

// ---------------- edge pass 3: hAgg[d] += hW[s] * (ex / ssum[d]) --------------
__global__ void k_edge3(const int* __restrict__ src, const int* __restrict__ dst,
                        const float* __restrict__ ebuf, const float* __restrict__ ssum,
                        const float* __restrict__ hW, float* __restrict__ hAgg){
    int gid = blockIdx.x*256 + threadIdx.x;
    int e = gid >> 5;
    int c = (gid & 31) << 2;
    int s, d;
    if(e < NE_){ s = src[e]; d = dst[e]; } else { s = d = e - NE_; }
    float alpha = ebuf[e] / ssum[d];
    float4 v = *(const float4*)(hW + (size_t)s*128 + c);
    float* o = hAgg + (size_t)d*128 + c;
    atomicAdd(o+0, v.x*alpha);
    atomicAdd(o+1, v.y*alpha);
    atomicAdd(o+2, v.z*alpha);
    atomicAdd(o+3, v.w*alpha);
}

// ---------------- bias + gelu (in place) ----------------
__global__ void k_biasgelu(float* __restrict__ hAgg, const float* __restrict__ bias){
    int gid = blockIdx.x*256 + threadIdx.x;  // NN*128
    int c = gid & 127;
    hAgg[gid] = gelu_f(hAgg[gid] + bias[c]);
}

// ------- fused edge-FC + GRU input projection:
//   efrow = gelu([h3[src[e]] | h3[dst[e]]] @ fcW + fcb)           [128]
//   X3[(t*32+b)*192 + {z|r|h}] = efrow @ {Wz,Wr,Wh}[0:128] + bias [64 each]
__global__ void k_ef_x3(const float* __restrict__ h3, const int* __restrict__ src,
                        const int* __restrict__ dst, const float* __restrict__ fcW,
                        const float* __restrict__ fcb,
                        const float* __restrict__ Wz, const float* __restrict__ Wr,
                        const float* __restrict__ Wh, const float* __restrict__ bz,
                        const float* __restrict__ br, const float* __restrict__ bh,
                        float* __restrict__ X3){
    __shared__ float efs[16][128];
    int lane = threadIdx.x & 63;
    int wy = threadIdx.x >> 6;
    int e0 = blockIdx.x*16 + wy*4;

    // phase 1: edge-FC
    {
        float acc0[4] = {0,0,0,0}, acc1[4] = {0,0,0,0};
        #pragma unroll
        for(int half=0; half<2; half++){
            const float* rowp[4];
            #pragma unroll
            for(int i=0;i<4;i++){
                int n = (half==0) ? src[e0+i] : dst[e0+i];
                rowp[i] = h3 + (size_t)n*128;
            }
            #pragma unroll 2
            for(int k=0;k<128;k+=4){
                float4 av[4];
                #pragma unroll
                for(int i=0;i<4;i++) av[i] = *(const float4*)(rowp[i] + k);
                #pragma unroll
                for(int kk=0;kk<4;kk++){
                    int kw = half*128 + k + kk;
                    float w0 = fcW[(size_t)kw*128 + lane];
                    float w1 = fcW[(size_t)kw*128 + 64 + lane];
                    #pragma unroll
                    for(int i=0;i<4;i++){
                        float a = ((const float*)&av[i])[kk];
                        acc0[i] += a*w0;
                        acc1[i] += a*w1;
                    }
                }
            }
        }
        float b0 = fcb[lane], b1 = fcb[64+lane];
        #pragma unroll
        for(int i=0;i<4;i++){
            efs[wy*4+i][lane]      = gelu_f(acc0[i] + b0);
            efs[wy*4+i][64 + lane] = gelu_f(acc1[i] + b1);
        }
    }
    __syncthreads();
    // phase 2: project to z/r/h inputs
    {
        float accz[4] = {0,0,0,0}, accr[4] = {0,0,0,0}, acch[4] = {0,0,0,0};
        #pragma unroll 2
        for(int k=0;k<128;k+=4){
            #pragma unroll
            for(int kk=0;kk<4;kk++){
                float w0 = Wz[(size_t)(k+kk)*64 + lane];
                float w1 = Wr[(size_t)(k+kk)*64 + lane];
                float w2 = Wh[(size_t)(k+kk)*64 + lane];
                #pragma unroll
                for(int i=0;i<4;i++){
                    float a = efs[wy*4+i][k+kk];
                    accz[i] += a*w0;
                    accr[i] += a*w1;
                    acch[i] += a*w2;
                }
            }
        }
        float b0 = bz[lane], b1 = br[lane], b2 = bh[lane];
        #pragma unroll
        for(int i=0;i<4;i++){
            int e = e0 + i;
            int bb = e >> 12;       // graph
            int t  = e & 4095;      // timestep
            float* o = X3 + ((size_t)t*32 + bb)*192;
            o[lane]       = accz[i] + b0;
            o[64 + lane]  = accr[i] + b1;
            o[128 + lane] = acch[i] + b2;
        }
    }
}

// ---------------- GRU: 1 block per batch, hidden recurrence only --------------
__global__ void __launch_bounds__(128) k_gru(const float* __restrict__ X3,
                       const float* __restrict__ Wz, const float* __restrict__ Wr,
                       const float* __restrict__ Wh, float* __restrict__ out){
    int b = blockIdx.x;
    int t = threadIdx.x;        // 0..127
    __shared__ float hid[64];
    __shared__ float zs[64];
    __shared__ float rh[64];

    // phase-A role: output j of [z(0..63)|r(64..127)]; hidden-part weight column
    int j = t;
    const float* wA = (j < 64) ? (Wz + j) : (Wr + (j - 64));
    float WA[64];
    #pragma unroll
    for(int k=0;k<64;k++) WA[k] = wA[(size_t)(128+k)*64];

    // phase-B role: output o, half hh covers k in [32*hh, 32*hh+32)
    int o = t >> 1, hh = t & 1;
    float WB[32];
    #pragma unroll
    for(int k=0;k<32;k++) WB[k] = Wh[(size_t)(128 + hh*32 + k)*64 + o];

    if(t < 64) hid[t] = 0.f;
    __syncthreads();

    const float* x0 = X3 + (size_t)b*192;
    float nxA = x0[j];
    float nxB = x0[128 + o];

    for(int step=0; step<T_; step++){
        float xA = nxA, xB = nxB;
        if(step + 1 < T_){
            const float* nb = X3 + ((size_t)(step+1)*32 + b)*192;
            nxA = nb[j];
            nxB = nb[128 + o];
        }
        // phase A: s_j = x_j + hid . WA
        float s = xA;
        const float4* h4 = (const float4*)hid;
        #pragma unroll
        for(int kk=0;kk<16;kk++){
            float4 hv = h4[kk];
            s += hv.x*WA[4*kk] + hv.y*WA[4*kk+1] + hv.z*WA[4*kk+2] + hv.w*WA[4*kk+3];
        }
        float sig = 1.f/(1.f + __expf(-s));
        if(j < 64) zs[j] = sig;
        else       rh[j-64] = sig * hid[j-64];
        __syncthreads();
        // phase B: ht_o = lrelu(xh_o + rh . Wh_col, 0.01)
        float p = 0.f;
        const float4* r4 = (const float4*)(rh + hh*32);
        #pragma unroll
        for(int kk=0;kk<8;kk++){
            float4 rv = r4[kk];
            p += rv.x*WB[4*kk] + rv.y*WB[4*kk+1] + rv.z*WB[4*kk+2] + rv.w*WB[4*kk+3];
        }
        p += __shfl_xor(p, 1);
        float s2 = xB + p;
        float ht = (s2 > 0.f) ? s2 : 0.01f*s2;
        if(hh == 0){
            float z = zs[o];
            hid[o] = (1.f - z)*hid[o] + z*ht;
        }
        __syncthreads();
    }
    if(t < 64) out[(size_t)b*64 + t] = hid[t];
}

extern "C" void kernel_launch(void* const* d_in, const int* in_sizes, int n_in,
                              void* d_out, int out_size, void* d_ws, size_t ws_size,
                              hipStream_t stream) {
    const float* x    = (const float*)d_in[0];
    const int*   nidx = (const int*)d_in[1];
    const int*   src  = (const int*)d_in[2];
    const int*   dst  = src + NE_;
    const float* emb  = (const float*)d_in[3];
    const float* W1 = (const float*)d_in[4];
    const float* a1s = (const float*)d_in[5];
    const float* a1d = (const float*)d_in[6];
    const float* b1 = (const float*)d_in[7];
    const float* W2 = (const float*)d_in[8];
    const float* a2s = (const float*)d_in[9];
    const float* a2d = (const float*)d_in[10];
    const float* b2 = (const float*)d_in[11];
    const float* W3 = (const float*)d_in[12];
    const float* a3s = (const float*)d_in[13];
    const float* a3d = (const float*)d_in[14];
    const float* b3 = (const float*)d_in[15];
    const float* fcW = (const float*)d_in[16];
    const float* fcb = (const float*)d_in[17];
    const float* Wz = (const float*)d_in[18];
    const float* bz = (const float*)d_in[19];
    const float* Wr = (const float*)d_in[20];
    const float* br = (const float*)d_in[21];
    const float* Wh = (const float*)d_in[22];
    const float* bh = (const float*)d_in[23];
    float* out = (float*)d_out;

    // ---- workspace layout: 128 MB total ----
    // hAgg  [NN*128]                 activations / aggregation buffer (persistent)
    // X3    [NE*192]                 GRU input projections (written last)
    //   aliased INSIDE X3 (dead before X3 is written):
    //   bufA [NN*128], h64 [NN*64], ssrc/sdst/ssum/menc [NN each], ebuf [NE+NN]
    float* ws = (float*)d_ws;
    float* hAgg = ws;                          // NN*128
    float* X3   = hAgg + (size_t)NN_*128;      // NE*192
    float* bufA = X3;                          // NN*128   (alias)
    float* h64  = bufA + (size_t)NN_*128;      // NN*64    (alias)
    float* ssrc = h64  + (size_t)NN_*64;       // NN       (alias)
    float* sdst = ssrc + NN_;                  // NN
    float* ssum = sdst + NN_;                  // NN
    unsigned* menc = (unsigned*)(ssum + NN_);  // NN
    float* ebuf = (float*)menc + NN_;          // NE+NN

    const int EP = NE_ + NN_;                  // 196608 edges incl self-loops

    k_embed<<<NN_*64/256, 256, 0, stream>>>(x, nidx, emb, h64);

    const float* Ws[3]  = {W1, W2, W3};
    const float* as_[3] = {a1s, a2s, a3s};
    const float* ad_[3] = {a1d, a2d, a3d};
    const float* bs[3]  = {b1, b2, b3};

    for(int l=0; l<3; l++){
        // GEMM first (reads prev activations from hAgg for l>0), then zero hAgg
        if(l == 0)
            k_gemm_node<64><<<NN_/16, 256, 0, stream>>>(h64, Ws[l], bufA);
        else
            k_gemm_node<128><<<NN_/16, 256, 0, stream>>>(hAgg, Ws[l], bufA);
        k_zero<<<2048, 256, 0, stream>>>(hAgg, NN_*128);
        k_zero<<<512, 256, 0, stream>>>(ssum, 2*NN_);   // ssum + menc (contiguous)
        k_rowdots<<<NN_/4, 256, 0, stream>>>(bufA, as_[l], ad_[l], ssrc, sdst);
        k_edge1<<<EP/256, 256, 0, stream>>>(src, dst, ssrc, sdst, ebuf, menc);
        k_edge2<<<EP/256, 256, 0, stream>>>(dst, menc, ebuf, ssum);
        k_edge3<<<EP*32/256, 256, 0, stream>>>(src, dst, ebuf, ssum, bufA, hAgg);
        k_biasgelu<<<NN_*128/256, 256, 0, stream>>>(hAgg, bs[l]);
    }

    k_ef_x3<<<NE_/16, 256, 0, stream>>>(hAgg, src, dst, fcW, fcb,
                                        Wz, Wr, Wh, bz, br, bh, X3);
    k_gru<<<B_, 128, 0, stream>>>(X3, Wz, Wr, Wh, out);
}

// Round 3
// 4931.412 us; speedup vs baseline: 1.1101x; 1.1101x over previous
//
#include <hip/hip_runtime.h>
#include <hip/hip_bf16.h>
#include <math.h>

#define NN_ 65536
#define NE_ 131072
#define B_  32
#define T_  4096

__device__ __forceinline__ float gelu_f(float x){
    return 0.5f*x*(1.0f + erff(x*0.70710678118654752f));
}

// monotonic float<->uint encoding for atomicMax on floats
__device__ __forceinline__ unsigned enc_f(float f){
    unsigned b = __float_as_uint(f);
    return (b & 0x80000000u) ? ~b : (b | 0x80000000u);
}
__device__ __forceinline__ float dec_f(unsigned u){
    return (u & 0x80000000u) ? __uint_as_float(u ^ 0x80000000u) : __uint_as_float(~u);
}

// broadcast lane l's value of v to all lanes (compile-time l -> v_readlane)
__device__ __forceinline__ float rdlane(float v, int l){
    return __int_as_float(__builtin_amdgcn_readlane(__float_as_int(v), l));
}

// ---------------- zero ----------------
__global__ void k_zero(float* p, int n){
    int i = blockIdx.x*blockDim.x + threadIdx.x;
    int stride = gridDim.x*blockDim.x;
    for(; i<n; i+=stride) p[i] = 0.f;
}

// ---------------- embed concat: h64[n][c] = c<32 ? x[n][c] : emb[nidx[n]][c-32] ----
__global__ void k_embed(const float* __restrict__ x, const int* __restrict__ nidx,
                        const float* __restrict__ emb, float* __restrict__ h64){
    int gid = blockIdx.x*256 + threadIdx.x;
    int n = gid >> 6, c = gid & 63;
    float v = (c < 32) ? x[(size_t)n*32 + c] : emb[(size_t)nidx[n]*32 + (c-32)];
    h64[gid] = v;
}

// ---------------- node GEMM: C[M,128] = A[M,K] @ W[K,128] ----------------
template<int K>
__global__ void k_gemm_node(const float* __restrict__ A, const float* __restrict__ W,
                            float* __restrict__ C){
    int lane = threadIdx.x & 63;
    int wy = threadIdx.x >> 6;
    int r0 = blockIdx.x*16 + wy*4;
    const float* a0 = A + (size_t)r0*K;
    float acc0[4] = {0,0,0,0}, acc1[4] = {0,0,0,0};
    #pragma unroll 4
    for(int k=0;k<K;k+=4){
        float4 av[4];
        #pragma unroll
        for(int i=0;i<4;i++) av[i] = *(const float4*)(a0 + (size_t)i*K + k);
        #pragma unroll
        for(int kk=0;kk<4;kk++){
            float w0 = W[(size_t)(k+kk)*128 + lane];
            float w1 = W[(size_t)(k+kk)*128 + 64 + lane];
            #pragma unroll
            for(int i=0;i<4;i++){
                float a = ((const float*)&av[i])[kk];
                acc0[i] += a*w0;
                acc1[i] += a*w1;
            }
        }
    }
    #pragma unroll
    for(int i=0;i<4;i++){
        C[(size_t)(r0+i)*128 + lane]      = acc0[i];
        C[(size_t)(r0+i)*128 + 64 + lane] = acc1[i];
    }
}

// ---------------- per-row dots: ssrc = hW . a_s, sdst = hW . a_d --------------
__global__ void k_rowdots(const float* __restrict__ hW, const float* __restrict__ as_,
                          const float* __restrict__ ad_, float* __restrict__ ssrc,
                          float* __restrict__ sdst){
    int lane = threadIdx.x & 63;
    int row = blockIdx.x*4 + (threadIdx.x >> 6);
    const float* hp = hW + (size_t)row*128;
    float h0 = hp[lane], h1 = hp[lane+64];
    float d0 = h0*as_[lane] + h1*as_[lane+64];
    float d1 = h0*ad_[lane] + h1*ad_[lane+64];
    #pragma unroll
    for(int off=32; off; off>>=1){
        d0 += __shfl_xor(d0, off);
        d1 += __shfl_xor(d1, off);
    }
    if(lane==0){ ssrc[row] = d0; sdst[row] = d1; }
}

// ---------------- edge pass 1: e = lrelu(ssrc[s]+sdst[d]); max into m[d] ------
__global__ void k_edge1(const int* __restrict__ src, const int* __restrict__ dst,
                        const float* __restrict__ ssrc, const float* __restrict__ sdst,
                        float* __restrict__ ebuf, unsigned* __restrict__ menc){
    int e = blockIdx.x*256 + threadIdx.x;   // e < NE_+NN_
    int s, d;
    if(e < NE_){ s = src[e]; d = dst[e]; } else { s = d = e - NE_; }
    float v = ssrc[s] + sdst[d];
    v = (v > 0.f) ? v : 0.2f*v;
    ebuf[e] = v;
    atomicMax(&menc[d], enc_f(v));
}

// ---------------- edge pass 2: ex = exp(e - m[d]); sum into ssum[d] -----------
__global__ void k_edge2(const int* __restrict__ dst, const unsigned* __restrict__ menc,
                        float* __restrict__ ebuf, float* __restrict__ ssum){
    int e = blockIdx.x*256 + threadIdx.x;
    int d = (e < NE_) ? dst[e] : (e - NE_);
    float m = dec_f(menc[d]);
    float ex = __expf(ebuf[e] - m);
    ebuf[e] = ex;
    atomicAdd(&ssum[d], ex);
}

// ---------------- edge pass 3: hAgg[d] += hW[s] * (ex / ssum[d]) --------------
__global__ void k_edge3(const int* __restrict__ src, const int* __restrict__ dst,
                        const float* __restrict__ ebuf, const float* __restrict__ ssum,
                        const float* __restrict__ hW, float* __restrict__ hAgg){
    int gid = blockIdx.x*256 + threadIdx.x;
    int e = gid >> 5;
    int c = (gid & 31) << 2;
    int s, d;
    if(e < NE_){ s = src[e]; d = dst[e]; } else { s = d = e - NE_; }
    float alpha = ebuf[e] / ssum[d];
    float4 v = *(const float4*)(hW + (size_t)s*128 + c);
    float* o = hAgg + (size_t)d*128 + c;
    atomicAdd(o+0, v.x*alpha);
    atomicAdd(o+1, v.y*alpha);
    atomicAdd(o+2, v.z*alpha);
    atomicAdd(o+3, v.w*alpha);
}

// ---------------- bias + gelu (in place) ----------------
__global__ void k_biasgelu(float* __restrict__ hAgg, const float* __restrict__ bias){
    int gid = blockIdx.x*256 + threadIdx.x;  // NN*128
    int c = gid & 127;
    hAgg[gid] = gelu_f(hAgg[gid] + bias[c]);
}

// ------- fused edge-FC + GRU input projection:
//   efrow = gelu([h3[src[e]] | h3[dst[e]]] @ fcW + fcb)           [128]
//   X3[(t*32+b)*192 + {z|r|h}] = efrow @ {Wz,Wr,Wh}[0:128] + bias [64 each]
__global__ void k_ef_x3(const float* __restrict__ h3, const int* __restrict__ src,
                        const int* __restrict__ dst, const float* __restrict__ fcW,
                        const float* __restrict__ fcb,
                        const float* __restrict__ Wz, const float* __restrict__ Wr,
                        const float* __restrict__ Wh, const float* __restrict__ bz,
                        const float* __restrict__ br, const float* __restrict__ bh,
                        float* __restrict__ X3){
    __shared__ float efs[16][128];
    int lane = threadIdx.x & 63;
    int wy = threadIdx.x >> 6;
    int e0 = blockIdx.x*16 + wy*4;

    // phase 1: edge-FC
    {
        float acc0[4] = {0,0,0,0}, acc1[4] = {0,0,0,0};
        #pragma unroll
        for(int half=0; half<2; half++){
            const float* rowp[4];
            #pragma unroll
            for(int i=0;i<4;i++){
                int n = (half==0) ? src[e0+i] : dst[e0+i];
                rowp[i] = h3 + (size_t)n*128;
            }
            #pragma unroll 2
            for(int k=0;k<128;k+=4){
                float4 av[4];
                #pragma unroll
                for(int i=0;i<4;i++) av[i] = *(const float4*)(rowp[i] + k);
                #pragma unroll
                for(int kk=0;kk<4;kk++){
                    int kw = half*128 + k + kk;
                    float w0 = fcW[(size_t)kw*128 + lane];
                    float w1 = fcW[(size_t)kw*128 + 64 + lane];
                    #pragma unroll
                    for(int i=0;i<4;i++){
                        float a = ((const float*)&av[i])[kk];
                        acc0[i] += a*w0;
                        acc1[i] += a*w1;
                    }
                }
            }
        }
        float b0 = fcb[lane], b1 = fcb[64+lane];
        #pragma unroll
        for(int i=0;i<4;i++){
            efs[wy*4+i][lane]      = gelu_f(acc0[i] + b0);
            efs[wy*4+i][64 + lane] = gelu_f(acc1[i] + b1);
        }
    }
    __syncthreads();
    // phase 2: project to z/r/h inputs
    {
        float accz[4] = {0,0,0,0}, accr[4] = {0,0,0,0}, acch[4] = {0,0,0,0};
        #pragma unroll 2
        for(int k=0;k<128;k+=4){
            #pragma unroll
            for(int kk=0;kk<4;kk++){
                float w0 = Wz[(size_t)(k+kk)*64 + lane];
                float w1 = Wr[(size_t)(k+kk)*64 + lane];
                float w2 = Wh[(size_t)(k+kk)*64 + lane];
                #pragma unroll
                for(int i=0;i<4;i++){
                    float a = efs[wy*4+i][k+kk];
                    accz[i] += a*w0;
                    accr[i] += a*w1;
                    acch[i] += a*w2;
                }
            }
        }
        float b0 = bz[lane], b1 = br[lane], b2 = bh[lane];
        #pragma unroll
        for(int i=0;i<4;i++){
            int e = e0 + i;
            int bb = e >> 12;       // graph
            int t  = e & 4095;      // timestep
            float* o = X3 + ((size_t)t*32 + bb)*192;
            o[lane]       = accz[i] + b0;
            o[64 + lane]  = accr[i] + b1;
            o[128 + lane] = acch[i] + b2;
        }
    }
}

// ---------------- GRU: 1 wave per batch, all-register recurrence --------------
// lane j owns output j. hid distributed 1 elem/lane; broadcasts via v_readlane
// (compile-time lane index), weight columns in VGPRs. No LDS, no barriers.
__global__ void __launch_bounds__(64) k_gru(const float* __restrict__ X3,
                       const float* __restrict__ Wz, const float* __restrict__ Wr,
                       const float* __restrict__ Wh, float* __restrict__ out){
    int b = blockIdx.x;
    int j = threadIdx.x;        // 0..63

    // hidden-part weight columns (rows 128..191, col j)
    float wz[64], wr[64], wh[64];
    #pragma unroll
    for(int k=0;k<64;k++){
        wz[k] = Wz[(size_t)(128+k)*64 + j];
        wr[k] = Wr[(size_t)(128+k)*64 + j];
        wh[k] = Wh[(size_t)(128+k)*64 + j];
    }

    float h = 0.f;
    const float* x0 = X3 + (size_t)b*192;
    float xz = x0[j], xr = x0[64+j], xh = x0[128+j];

    for(int step=0; step<T_; step++){
        float nxz, nxr, nxh;
        if(step + 1 < T_){
            const float* np = X3 + ((size_t)(step+1)*32 + b)*192;
            nxz = np[j]; nxr = np[64+j]; nxh = np[128+j];
        } else { nxz = nxr = nxh = 0.f; }

        // z_j, r_j = sigmoid(x + sum_k hid[k] * W[128+k][j])
        float az0 = xz, az1 = 0.f, ar0 = xr, ar1 = 0.f;
        #pragma unroll
        for(int k=0;k<64;k+=2){
            float h0 = rdlane(h, k);
            float h1 = rdlane(h, k+1);
            az0 += h0*wz[k];   ar0 += h0*wr[k];
            az1 += h1*wz[k+1]; ar1 += h1*wr[k+1];
        }
        float z = 1.f/(1.f + __expf(-(az0+az1)));
        float r = 1.f/(1.f + __expf(-(ar0+ar1)));
        float rh = r*h;

        // ht_j = lrelu(xh + sum_k rh[k] * Wh[128+k][j], 0.01)
        float ah0 = xh, ah1 = 0.f;
        #pragma unroll
        for(int k=0;k<64;k+=2){
            float r0 = rdlane(rh, k);
            float r1 = rdlane(rh, k+1);
            ah0 += r0*wh[k];
            ah1 += r1*wh[k+1];
        }
        float s2 = ah0 + ah1;
        float ht = (s2 > 0.f) ? s2 : 0.01f*s2;

        h = (1.f - z)*h + z*ht;
        xz = nxz; xr = nxr; xh = nxh;
    }
    out[(size_t)b*64 + j] = h;
}

extern "C" void kernel_launch(void* const* d_in, const int* in_sizes, int n_in,
                              void* d_out, int out_size, void* d_ws, size_t ws_size,
                              hipStream_t stream) {
    const float* x    = (const float*)d_in[0];
    const int*   nidx = (const int*)d_in[1];
    const int*   src  = (const int*)d_in[2];
    const int*   dst  = src + NE_;
    const float* emb  = (const float*)d_in[3];
    const float* W1 = (const float*)d_in[4];
    const float* a1s = (const float*)d_in[5];
    const float* a1d = (const float*)d_in[6];
    const float* b1 = (const float*)d_in[7];
    const float* W2 = (const float*)d_in[8];
    const float* a2s = (const float*)d_in[9];
    const float* a2d = (const float*)d_in[10];
    const float* b2 = (const float*)d_in[11];
    const float* W3 = (const float*)d_in[12];
    const float* a3s = (const float*)d_in[13];
    const float* a3d = (const float*)d_in[14];
    const float* b3 = (const float*)d_in[15];
    const float* fcW = (const float*)d_in[16];
    const float* fcb = (const float*)d_in[17];
    const float* Wz = (const float*)d_in[18];
    const float* bz = (const float*)d_in[19];
    const float* Wr = (const float*)d_in[20];
    const float* br = (const float*)d_in[21];
    const float* Wh = (const float*)d_in[22];
    const float* bh = (const float*)d_in[23];
    float* out = (float*)d_out;

    // ---- workspace layout: 128 MB total ----
    float* ws = (float*)d_ws;
    float* hAgg = ws;                          // NN*128
    float* X3   = hAgg + (size_t)NN_*128;      // NE*192
    float* bufA = X3;                          // NN*128   (alias)
    float* h64  = bufA + (size_t)NN_*128;      // NN*64    (alias)
    float* ssrc = h64  + (size_t)NN_*64;       // NN       (alias)
    float* sdst = ssrc + NN_;                  // NN
    float* ssum = sdst + NN_;                  // NN
    unsigned* menc = (unsigned*)(ssum + NN_);  // NN
    float* ebuf = (float*)menc + NN_;          // NE+NN

    const int EP = NE_ + NN_;                  // 196608 edges incl self-loops

    k_embed<<<NN_*64/256, 256, 0, stream>>>(x, nidx, emb, h64);

    const float* Ws[3]  = {W1, W2, W3};
    const float* as_[3] = {a1s, a2s, a3s};
    const float* ad_[3] = {a1d, a2d, a3d};
    const float* bs[3]  = {b1, b2, b3};

    for(int l=0; l<3; l++){
        // GEMM first (reads prev activations from hAgg for l>0), then zero hAgg
        if(l == 0)
            k_gemm_node<64><<<NN_/16, 256, 0, stream>>>(h64, Ws[l], bufA);
        else
            k_gemm_node<128><<<NN_/16, 256, 0, stream>>>(hAgg, Ws[l], bufA);
        k_zero<<<2048, 256, 0, stream>>>(hAgg, NN_*128);
        k_zero<<<512, 256, 0, stream>>>(ssum, 2*NN_);   // ssum + menc (contiguous)
        k_rowdots<<<NN_/4, 256, 0, stream>>>(bufA, as_[l], ad_[l], ssrc, sdst);
        k_edge1<<<EP/256, 256, 0, stream>>>(src, dst, ssrc, sdst, ebuf, menc);
        k_edge2<<<EP/256, 256, 0, stream>>>(dst, menc, ebuf, ssum);
        k_edge3<<<EP*32/256, 256, 0, stream>>>(src, dst, ebuf, ssum, bufA, hAgg);
        k_biasgelu<<<NN_*128/256, 256, 0, stream>>>(hAgg, bs[l]);
    }

    k_ef_x3<<<NE_/16, 256, 0, stream>>>(hAgg, src, dst, fcW, fcb,
                                        Wz, Wr, Wh, bz, br, bh, X3);
    k_gru<<<B_, 64, 0, stream>>>(X3, Wz, Wr, Wh, out);
}